// Round 12
// baseline (826.028 us; speedup 1.0000x reference)
//
#include <hip/hip_runtime.h>
#include <math.h>

#define N_TOK 8192
#define DIM   768
#define MEMN  10000
#define MEMP  10240            // padded to 40*256
#define TQ    64
#define TM    256
#define NSPLIT 2
#define TILES_PER_SPLIT 20

constexpr float SCALE = 0.036084391824351615f;  // 1/sqrt(768)

typedef short bf16x8 __attribute__((ext_vector_type(8)));
typedef float f32x4  __attribute__((ext_vector_type(4)));

__device__ __forceinline__ unsigned short f2bf(float f) {
    unsigned u = __float_as_uint(f);
    unsigned r = (u + 0x7fffu + ((u >> 16) & 1u)) >> 16;   // RTN-even
    return (unsigned short)r;
}

// ---------------------------------------------------------------------------
// prep_all: ONE launch for all operand conversions (round-18, VERIFIED).
//   blocks [0,640):        memF   blocks [640,4480):  memS
//   blocks [4480,5632):    w12T   blocks [5632,6208): w2T
// ---------------------------------------------------------------------------
__global__ __launch_bounds__(256)
void prep_all(const float* __restrict__ mem, const float* __restrict__ w1,
              const float* __restrict__ w2,
              unsigned short* __restrict__ memF, unsigned short* __restrict__ memS,
              unsigned short* __restrict__ w12T, unsigned short* __restrict__ w2T)
{
    __shared__ float T[32][65];
    const int bid = blockIdx.x;

    if (bid < 640) {
        const int mb = bid;
        const bool zero = (mb >= MEMN / 16);
#pragma unroll
        for (int it = 0; it < 6; ++it) {
            const int s   = it * 256 + threadIdx.x;      // 0..1535
            const int kc  = s >> 6;
            const int r   = s & 63;
            const int l16 = r >> 2, q = r & 3;
            unsigned short o[8];
            if (!zero) {
                const float* src = &mem[(size_t)(mb * 16 + l16) * DIM + kc * 32 + q * 8];
                float4 v0 = *(const float4*)src;
                float4 v1 = *(const float4*)(src + 4);
                o[0] = f2bf(v0.x); o[1] = f2bf(v0.y); o[2] = f2bf(v0.z); o[3] = f2bf(v0.w);
                o[4] = f2bf(v1.x); o[5] = f2bf(v1.y); o[6] = f2bf(v1.z); o[7] = f2bf(v1.w);
            } else {
#pragma unroll
                for (int j = 0; j < 8; ++j) o[j] = 0;
            }
            *(uint4*)&memF[((size_t)mb * 24 + kc) * 512 + r * 8] = *(const uint4*)o;
        }
    } else if (bid < 4480) {
        const int rr = bid - 640;
        const int mc = rr % 320;
        const int d0 = (rr / 320) * 64;
        const int tx = threadIdx.x & 63;
        const int ty = threadIdx.x >> 6;
#pragma unroll
        for (int i = 0; i < 8; ++i) {
            const int row = ty + 4 * i;                  // 0..31
            const int m   = mc * 32 + row;
            T[row][tx] = (m < MEMN) ? mem[(size_t)m * DIM + d0 + tx] : 0.f;
        }
        __syncthreads();
        const int dbl = threadIdx.x >> 6;
        const int r   = threadIdx.x & 63;
        const int l16 = r >> 2, q = r & 3;
        unsigned short o[8];
#pragma unroll
        for (int j = 0; j < 8; ++j) o[j] = f2bf(T[q * 8 + j][dbl * 16 + l16]);
        *(uint4*)&memS[((size_t)(d0 / 16 + dbl) * 320 + mc) * 512 + r * 8] = *(const uint4*)o;
    } else if (bid < 5632) {
        const int rr = bid - 4480;
        const int kb = (rr % 48) * 32;
        const int nb = (rr / 48) * 32;
        const int tx = threadIdx.x & 31, ty = threadIdx.x >> 5;
#pragma unroll
        for (int i = 0; i < 4; ++i) {
            int k = kb + ty + 8 * i;
            float v = w1[(size_t)(768 + k) * DIM + nb + tx];
            if (kb < 768) v += w1[(size_t)k * DIM + nb + tx];
            T[ty + 8 * i][tx] = v;              // T[k_local][n_local]
        }
        __syncthreads();
        if (threadIdx.x < 128) {
            const int sub = threadIdx.x >> 6;
            const int r   = threadIdx.x & 63;
            const int l16 = r >> 2, q = r & 3;
            unsigned short o[8];
#pragma unroll
            for (int j = 0; j < 8; ++j) o[j] = f2bf(T[q * 8 + j][sub * 16 + l16]);
            const int n16 = (nb >> 4) + sub;
            const int kc  = kb >> 5;
            *(uint4*)&w12T[((size_t)n16 * 48 + kc) * 512 + r * 8] = *(const uint4*)o;
        }
    } else {
        const int rr = bid - 5632;
        const int kb = (rr % 24) * 32;
        const int nb = (rr / 24) * 32;
        const int tx = threadIdx.x & 31, ty = threadIdx.x >> 5;
#pragma unroll
        for (int i = 0; i < 4; ++i)
            T[ty + 8 * i][tx] = w2[(size_t)(kb + ty + 8 * i) * DIM + nb + tx];
        __syncthreads();
        if (threadIdx.x < 128) {
            const int sub = threadIdx.x >> 6;
            const int r   = threadIdx.x & 63;
            const int l16 = r >> 2, q = r & 3;
            unsigned short o[8];
#pragma unroll
            for (int j = 0; j < 8; ++j) o[j] = f2bf(T[q * 8 + j][sub * 16 + l16]);
            const int n16 = (nb >> 4) + sub;
            const int kc  = kb >> 5;
            *(uint4*)&w2T[((size_t)n16 * 24 + kc) * 512 + r * 8] = *(const uint4*)o;
        }
    }
}

// ---------------------------------------------------------------------------
// Fused MFMA attention. Round-15 main loop (VERIFIED 599-613 us) UNCHANGED.
// Q staged directly from fp32 cs.
// ---------------------------------------------------------------------------
template <int PLAIN>
__global__ __launch_bounds__(1024, 4)
void attn_mfma(const float* __restrict__ cs, const unsigned short* __restrict__ memF,
               const unsigned short* __restrict__ memS,
               float* __restrict__ retrRaw, float* __restrict__ Lvec)
{
    __shared__ __align__(16) unsigned short Qs[64 * 768];   // 96 KB, xor-swizzled
    __shared__ __align__(16) unsigned short Ps[64 * 256];   // 32 KB, xor-swizzled
    __shared__ float Lred[16][64];                          // 4 KB, L block-reduce

    const int tid    = threadIdx.x;
    const int w      = tid >> 6;         // wave 0..15
    const int lane   = tid & 63;
    const int quad   = lane >> 4;        // 0..3
    const int l16    = lane & 15;
    const int fr     = ((l16 << 2) | quad) << 3;   // fragment-linear lane offset (ushorts)

    const int split = blockIdx.y;
    const int q0    = blockIdx.x * TQ;   // 0..8128 step 64

    const int dbase  = w * 48;           // phase-2 d-strip per wave (3 x 16)
    const int mstrip = w * 16;           // phase-1 m-strip per wave (1 x 16)

    // ---- stage Q tile (64 rows) from fp32, convert to bf16, swizzled ----
    {
        const int qr  = tid >> 4;            // 0..63
        const int db0 = tid & 15;
        const float* src = cs + (size_t)(q0 + qr) * DIM;
        const int sw = qr & 7;
#pragma unroll
        for (int i = 0; i < 6; ++i) {
            int db = db0 + i * 16;           // 0..95 (blocks of 8 bf16)
            float4 v0 = *(const float4*)&src[db * 8];
            float4 v1 = *(const float4*)&src[db * 8 + 4];
            unsigned short o[8];
            o[0] = f2bf(v0.x); o[1] = f2bf(v0.y); o[2] = f2bf(v0.z); o[3] = f2bf(v0.w);
            o[4] = f2bf(v1.x); o[5] = f2bf(v1.y); o[6] = f2bf(v1.z); o[7] = f2bf(v1.w);
            *(uint4*)&Qs[qr * 768 + ((db ^ sw) << 3)] = *(const uint4*)o;
        }
    }
    __syncthreads();

    f32x4 oacc[4][3];
#pragma unroll
    for (int a = 0; a < 4; ++a)
#pragma unroll
        for (int b = 0; b < 3; ++b) oacc[a][b] = (f32x4){0.f, 0.f, 0.f, 0.f};
    float lsum[4][4];
#pragma unroll
    for (int a = 0; a < 4; ++a)
#pragma unroll
        for (int r = 0; r < 4; ++r) lsum[a][r] = 0.f;

    const int xsw = l16 & 7;

    for (int st = 0; st < TILES_PER_SPLIT; ++st) {
        const int m0  = (split * TILES_PER_SPLIT + st) * TM;
        const int mc0 = m0 >> 5;

        // ---- phase 1: S[64 x 256]; wave w covers m-strip mstrip..+16 ----
        f32x4 sacc[4];
#pragma unroll
        for (int a = 0; a < 4; ++a) sacc[a] = (f32x4){0.f, 0.f, 0.f, 0.f};

        const unsigned short* fb = memF + ((size_t)(m0 >> 4) + w) * 12288 + fr;

        bf16x8 pb[2];
        pb[0] = *(const bf16x8*)(fb);
        pb[1] = *(const bf16x8*)(fb + 512);

#pragma unroll
        for (int ks = 0; ks < 24; ++ks) {
            const int xq = (((ks << 2) + quad) ^ xsw) << 3;
            bf16x8 a0 = *(const bf16x8*)&Qs[l16 * 768 + xq];
            bf16x8 a1 = *(const bf16x8*)&Qs[(16 + l16) * 768 + xq];
            bf16x8 a2 = *(const bf16x8*)&Qs[(32 + l16) * 768 + xq];
            bf16x8 a3 = *(const bf16x8*)&Qs[(48 + l16) * 768 + xq];
            bf16x8 b = pb[ks & 1];
            sacc[0] = __builtin_amdgcn_mfma_f32_16x16x32_bf16(a0, b, sacc[0], 0, 0, 0);
            sacc[1] = __builtin_amdgcn_mfma_f32_16x16x32_bf16(a1, b, sacc[1], 0, 0, 0);
            sacc[2] = __builtin_amdgcn_mfma_f32_16x16x32_bf16(a2, b, sacc[2], 0, 0, 0);
            sacc[3] = __builtin_amdgcn_mfma_f32_16x16x32_bf16(a3, b, sacc[3], 0, 0, 0);
            if (ks < 22) pb[ks & 1] = *(const bf16x8*)(fb + (ks + 2) * 512);
        }

        __syncthreads();   // barrier A

        // ---- exp + P->LDS (bf16, swizzled) + row-sum accumulation ----
        {
            const int mloc = mstrip + l16;               // 0..255
            const bool ok  = (m0 + mloc) < MEMN;
#pragma unroll
            for (int qt = 0; qt < 4; ++qt)
#pragma unroll
                for (int r = 0; r < 4; ++r) {
                    float p = ok ? __expf(sacc[qt][r] * SCALE) : 0.f;
                    const int q = qt * 16 + quad * 4 + r;     // 0..63
                    lsum[qt][r] += p;
                    Ps[q * 256 + (((mloc >> 3) ^ (q & 7)) << 3) + (mloc & 7)] = f2bf(p);
                }
        }

        __syncthreads();   // barrier B

        // ---- phase 2: O += P * Mem; depth-2 register prefetch of B-frags ----
        const unsigned short* msp = memS + ((size_t)(3 * w) * 320 + mc0) * 512 + fr;
        bf16x8 cb[2][3];
#pragma unroll
        for (int nt = 0; nt < 3; ++nt) {
            cb[0][nt] = *(const bf16x8*)(msp + (size_t)nt * 163840);
            cb[1][nt] = *(const bf16x8*)(msp + (size_t)nt * 163840 + 512);
        }

#pragma unroll
        for (int ks = 0; ks < 8; ++ks) {
            const int xp = (((ks << 2) + quad) ^ xsw) << 3;
            bf16x8 pa0 = *(const bf16x8*)&Ps[l16 * 256 + xp];
            bf16x8 pa1 = *(const bf16x8*)&Ps[(16 + l16) * 256 + xp];
            bf16x8 pa2 = *(const bf16x8*)&Ps[(32 + l16) * 256 + xp];
            bf16x8 pa3 = *(const bf16x8*)&Ps[(48 + l16) * 256 + xp];
            const bool dopf = (ks < 6);
#pragma unroll
            for (int nt = 0; nt < 3; ++nt) {
                oacc[0][nt] = __builtin_amdgcn_mfma_f32_16x16x32_bf16(pa0, cb[ks & 1][nt], oacc[0][nt], 0, 0, 0);
                oacc[1][nt] = __builtin_amdgcn_mfma_f32_16x16x32_bf16(pa1, cb[ks & 1][nt], oacc[1][nt], 0, 0, 0);
                oacc[2][nt] = __builtin_amdgcn_mfma_f32_16x16x32_bf16(pa2, cb[ks & 1][nt], oacc[2][nt], 0, 0, 0);
                oacc[3][nt] = __builtin_amdgcn_mfma_f32_16x16x32_bf16(pa3, cb[ks & 1][nt], oacc[3][nt], 0, 0, 0);
                if (dopf) cb[ks & 1][nt] = *(const bf16x8*)(msp + (size_t)nt * 163840 + (ks + 2) * 512);
            }
        }
    }

    // ---- epilogue: combine O and L across splits ----
    float* ob = retrRaw + (PLAIN ? (size_t)split * ((size_t)N_TOK * DIM) : (size_t)0);
#pragma unroll
    for (int qt = 0; qt < 4; ++qt)
#pragma unroll
        for (int nt = 0; nt < 3; ++nt)
#pragma unroll
            for (int r = 0; r < 4; ++r) {
                const size_t idx = (size_t)(q0 + qt * 16 + quad * 4 + r) * DIM + dbase + nt * 16 + l16;
                if (PLAIN)
                    ob[idx] = oacc[qt][nt][r];
                else
                    __hip_atomic_fetch_add(&ob[idx], oacc[qt][nt][r],
                                           __ATOMIC_RELAXED, __HIP_MEMORY_SCOPE_AGENT);
            }

#pragma unroll
    for (int qt = 0; qt < 4; ++qt)
#pragma unroll
        for (int r = 0; r < 4; ++r) {
            float v = lsum[qt][r];
#pragma unroll
            for (int off = 1; off < 16; off <<= 1) v += __shfl_xor(v, off);
            if (l16 == 0) {
                if (PLAIN)
                    Lred[w][qt * 16 + quad * 4 + r] = v;
                else
                    __hip_atomic_fetch_add(&Lvec[q0 + qt * 16 + quad * 4 + r], v,
                                           __ATOMIC_RELAXED, __HIP_MEMORY_SCOPE_AGENT);
            }
        }
    if (PLAIN) {
        __syncthreads();
        if (tid < 64) {
            float s = 0.f;
#pragma unroll
            for (int ww = 0; ww < 16; ++ww) s += Lred[ww][tid];
            Lvec[(size_t)split * N_TOK + q0 + tid] = s;
        }
    }
}

// ---------------------------------------------------------------------------
// Fused tail, round-19: 8 waves (512 thr), per-wave 6 n16-blocks (was 4 waves
// x 12).  Same LDS (75 KB -> 2 blocks/CU), so waves/CU doubles 8 -> 16
// (2 -> 4 per SIMD) -- the round-8-proven TLP x in-flight-loads lever applied
// to the tail.  Stage-1 rows split 8-ways (2 serial row-iters, was 4).
// ---------------------------------------------------------------------------
template <int PLAIN>
__global__ __launch_bounds__(512, 2)
void fused_tail(const float* __restrict__ retrRaw, const float* __restrict__ Lvec,
                const float* __restrict__ cs, const float* __restrict__ gw,
                const float* __restrict__ gb,
                const unsigned short* __restrict__ W12T, const float* __restrict__ fb1,
                const unsigned short* __restrict__ W2T,  const float* __restrict__ fb2,
                const float* __restrict__ gamma, const float* __restrict__ beta,
                float* __restrict__ out)
{
    __shared__ __align__(16) unsigned short XRl[6 * 4096];  // 48 KB: XR[16][1536] swizzled
    __shared__ __align__(16) unsigned short Hl[3 * 4096];   // 24 KB: h[16][768] swizzled
    __shared__ float red[2][8][16];

    const int tid  = threadIdx.x;
    const int w    = tid >> 6;           // wave 0..7
    const int lane = tid & 63;
    const int quad = lane >> 4;
    const int l16  = lane & 15;
    const int row0 = blockIdx.x * 16;
    const int nbase = w * 96;            // 6 x 16 output cols per wave
    const int xsw3 = l16 & 7;
    const int fr   = ((l16 << 2) | quad) << 3;     // fragment-linear lane offset
    const int nb16 = w * 6;                        // first n16-block of this wave

    // ================= stage 1: finalize 16 rows -> XRl =================
#pragma unroll
    for (int it = 0; it < 2; ++it) {
        const int rl = it * 8 + w;                 // local row 0..15
        const int row = row0 + rl;
        const float lv = PLAIN ? (Lvec[row] + Lvec[N_TOK + row]) : Lvec[row];
        const float rli = 1.0f / lv;
        const float* rr  = retrRaw + (size_t)row * DIM;
        const float* rr1 = retrRaw + (size_t)N_TOK * DIM + (size_t)row * DIM;
        const float* cr  = cs + (size_t)row * DIM;

        float4 rv[3], cv[3];
        float d = 0.f;
#pragma unroll
        for (int i = 0; i < 3; ++i) {
            const int c4 = i * 256 + lane * 4;
            float4 r = *(const float4*)&rr[c4];
            if (PLAIN) {
                float4 r1 = *(const float4*)&rr1[c4];
                r.x += r1.x; r.y += r1.y; r.z += r1.z; r.w += r1.w;
            }
            r.x *= rli; r.y *= rli; r.z *= rli; r.w *= rli;
            float4 c = *(const float4*)&cr[c4];
            float4 g1 = *(const float4*)&gw[c4];
            float4 g2 = *(const float4*)&gw[DIM + c4];
            d += c.x * g1.x + c.y * g1.y + c.z * g1.z + c.w * g1.w;
            d += r.x * g2.x + r.y * g2.y + r.z * g2.z + r.w * g2.w;
            rv[i] = r; cv[i] = c;
        }
#pragma unroll
        for (int off = 32; off > 0; off >>= 1) d += __shfl_xor(d, off);
        d += gb[0];
        const float g = 1.0f / (1.0f + __expf(-d));

        const int g8 = lane >> 1;                  // granule within 256-chunk
        const int lo = (lane & 1) * 4;
#pragma unroll
        for (int i = 0; i < 3; ++i) {
            ushort4 xo, ro;
            xo.x = f2bf(cv[i].x + g * rv[i].x); xo.y = f2bf(cv[i].y + g * rv[i].y);
            xo.z = f2bf(cv[i].z + g * rv[i].z); xo.w = f2bf(cv[i].w + g * rv[i].w);
            ro.x = f2bf(rv[i].x); ro.y = f2bf(rv[i].y);
            ro.z = f2bf(rv[i].z); ro.w = f2bf(rv[i].w);
            const int sw = ((g8 ^ (rl & 7)) << 3) + lo;
            *(ushort4*)&XRl[i * 4096 + rl * 256 + sw] = xo;
            *(ushort4*)&XRl[(3 + i) * 4096 + rl * 256 + sw] = ro;
        }
    }
    __syncthreads();

    // ================= stage 2: gemm1 (XRl @ W12T + b1 -> gelu -> Hl) =====
    f32x4 acc[6];
#pragma unroll
    for (int nt = 0; nt < 6; ++nt) acc[nt] = (f32x4){0.f, 0.f, 0.f, 0.f};

    bf16x8 b[6];
#pragma unroll
    for (int nt = 0; nt < 6; ++nt)
        b[nt] = *(const bf16x8*)&W12T[(size_t)(nb16 + nt) * 48 * 512 + fr];

#pragma unroll
    for (int ch = 0; ch < 6; ++ch) {
#pragma unroll
        for (int ks = 0; ks < 8; ++ks) {
            bf16x8 af = *(const bf16x8*)&XRl[ch * 4096 + l16 * 256 + ((((ks << 2) + quad) ^ xsw3) << 3)];
            int kn = ch * 8 + ks + 1;
            if (kn >= 48) kn = 0;                  // dummy wrap
#pragma unroll
            for (int nt = 0; nt < 6; ++nt) {
                acc[nt] = __builtin_amdgcn_mfma_f32_16x16x32_bf16(af, b[nt], acc[nt], 0, 0, 0);
                b[nt] = *(const bf16x8*)&W12T[((size_t)(nb16 + nt) * 48 + kn) * 512 + fr];
            }
        }
    }

    {
        float bv[6];
#pragma unroll
        for (int nt = 0; nt < 6; ++nt) bv[nt] = fb1[nbase + nt * 16 + l16];
#pragma unroll
        for (int nt = 0; nt < 6; ++nt) {
            const int col = nbase + nt * 16 + l16;
            const int cch = col >> 8;
            const int g8  = (col >> 3) & 31;
#pragma unroll
            for (int r = 0; r < 4; ++r) {
                const int rowl = quad * 4 + r;
                float v = acc[nt][r] + bv[nt];
                v = 0.5f * v * (1.0f + erff(v * 0.7071067811865476f));
                Hl[cch * 4096 + rowl * 256 + ((g8 ^ (rowl & 7)) << 3) + (l16 & 7)] = f2bf(v);
            }
        }
    }

    // prefetch gemm2 B while Hl writes drain
    bf16x8 b2[6];
#pragma unroll
    for (int nt = 0; nt < 6; ++nt)
        b2[nt] = *(const bf16x8*)&W2T[(size_t)(nb16 + nt) * 24 * 512 + fr];

    __syncthreads();

    // ================= stage 3: gemm2 (Hl @ W2T + b2 -> LayerNorm -> out) ==
    f32x4 acc2[6];
#pragma unroll
    for (int nt = 0; nt < 6; ++nt) acc2[nt] = (f32x4){0.f, 0.f, 0.f, 0.f};

#pragma unroll
    for (int ch = 0; ch < 3; ++ch) {
#pragma unroll
        for (int ks = 0; ks < 8; ++ks) {
            bf16x8 af = *(const bf16x8*)&Hl[ch * 4096 + l16 * 256 + ((((ks << 2) + quad) ^ xsw3) << 3)];
            int kn = ch * 8 + ks + 1;
            if (kn >= 24) kn = 0;                  // dummy wrap
#pragma unroll
            for (int nt = 0; nt < 6; ++nt) {
                acc2[nt] = __builtin_amdgcn_mfma_f32_16x16x32_bf16(af, b2[nt], acc2[nt], 0, 0, 0);
                b2[nt] = *(const bf16x8*)&W2T[((size_t)(nb16 + nt) * 24 + kn) * 512 + fr];
            }
        }
    }

    {
        float bv[6];
#pragma unroll
        for (int nt = 0; nt < 6; ++nt) bv[nt] = fb2[nbase + nt * 16 + l16];

        float v[6][4];
        float s1[4] = {0.f, 0.f, 0.f, 0.f}, s2[4] = {0.f, 0.f, 0.f, 0.f};
#pragma unroll
        for (int nt = 0; nt < 6; ++nt)
#pragma unroll
            for (int r = 0; r < 4; ++r) {
                float t = acc2[nt][r] + bv[nt];
                v[nt][r] = t;
                s1[r] += t;
                s2[r] += t * t;
            }
#pragma unroll
        for (int r = 0; r < 4; ++r) {
#pragma unroll
            for (int off = 1; off < 16; off <<= 1) {
                s1[r] += __shfl_xor(s1[r], off);
                s2[r] += __shfl_xor(s2[r], off);
            }
            if (l16 == 0) {
                red[0][w][quad * 4 + r] = s1[r];
                red[1][w][quad * 4 + r] = s2[r];
            }
        }
        __syncthreads();
#pragma unroll
        for (int r = 0; r < 4; ++r) {
            const int rl16 = quad * 4 + r;
            float t1 = 0.f, t2 = 0.f;
#pragma unroll
            for (int ww = 0; ww < 8; ++ww) {
                t1 += red[0][ww][rl16];
                t2 += red[1][ww][rl16];
            }
            const float mu  = t1 * (1.0f / 768.0f);
            const float var = fmaxf(t2 * (1.0f / 768.0f) - mu * mu, 0.f);
            const float rs  = rsqrtf(var + 1e-5f);
            const int row = row0 + rl16;
#pragma unroll
            for (int nt = 0; nt < 6; ++nt) {
                const int col = nbase + nt * 16 + l16;
                out[(size_t)row * DIM + col] = (v[nt][r] - mu) * rs * gamma[col] + beta[col];
            }
        }
    }
}

// ---------------------------------------------------------------------------
extern "C" void kernel_launch(void* const* d_in, const int* in_sizes, int n_in,
                              void* d_out, int out_size, void* d_ws, size_t ws_size,
                              hipStream_t stream)
{
    const float* cs  = (const float*)d_in[0];
    const float* mem = (const float*)d_in[1];
    const float* gw  = (const float*)d_in[2];
    const float* gb  = (const float*)d_in[3];
    const float* fw1 = (const float*)d_in[4];
    const float* fb1 = (const float*)d_in[5];
    const float* fw2 = (const float*)d_in[6];
    const float* fb2 = (const float*)d_in[7];
    const float* gam = (const float*)d_in[8];
    const float* bet = (const float*)d_in[9];
    float* out = (float*)d_out;

    char* ws = (char*)d_ws;
    // Layout A (atomic fallback, ~72.8 MB) / Layout B (plain, ~98 MB):
    const size_t PLAIN_WS = 97976320;
    const bool plain = (ws_size >= PLAIN_WS);

    unsigned short* memF = (unsigned short*)ws;                 // 15,728,640
    unsigned short* memS = (unsigned short*)(ws + 15728640);    // 15,728,640
    // (qH region ws+31457280..44040192 unused; kept for layout stability)
    float*          retr = (float*)(ws + 44040192);             // A: 25,165,824 / B: 50,331,648
    float*          Lvec;
    unsigned short* w12T;
    unsigned short* w2T;
    if (plain) {
        Lvec = (float*)(ws + 94371840);            // 65,536 (2 splits)
        w12T = (unsigned short*)(ws + 94437376);   // 2,359,296
        w2T  = (unsigned short*)(ws + 96796672);   // 1,179,648 -> end 97,976,320
    } else {
        Lvec = (float*)(ws + 69206016);            // 32,768
        w12T = (unsigned short*)(ws + 69238784);   // 2,359,296
        w2T  = (unsigned short*)(ws + 71598080);   // 1,179,648 -> end 72,777,728
    }

    if (!plain)
        hipMemsetAsync(retr, 0, 25165824 + 32768, stream);      // atomic path needs zeroed accum

    prep_all<<<6208, 256, 0, stream>>>(mem, fw1, fw2, memF, memS, w12T, w2T);

    if (plain) {
        attn_mfma<1><<<dim3(N_TOK / TQ, NSPLIT), 1024, 0, stream>>>(cs, memF, memS, retr, Lvec);
        fused_tail<1><<<N_TOK / 16, 512, 0, stream>>>(retr, Lvec, cs, gw, gb,
                                                      w12T, fb1, w2T, fb2, gam, bet, out);
    } else {
        attn_mfma<0><<<dim3(N_TOK / TQ, NSPLIT), 1024, 0, stream>>>(cs, memF, memS, retr, Lvec);
        fused_tail<0><<<N_TOK / 16, 512, 0, stream>>>(retr, Lvec, cs, gw, gb,
                                                      w12T, fb1, w2T, fb2, gam, bet, out);
    }
}

// Round 14
// 804.900 us; speedup vs baseline: 1.0262x; 1.0262x over previous
//
#include <hip/hip_runtime.h>
#include <math.h>

#define N_TOK 8192
#define DIM   768
#define MEMN  10000
#define MEMP  10240            // padded to 40*256
#define TQ    64
#define TM    256
#define NSPLIT 2
#define TILES_PER_SPLIT 20

constexpr float SCALE = 0.036084391824351615f;  // 1/sqrt(768)

typedef short bf16x8 __attribute__((ext_vector_type(8)));
typedef float f32x4  __attribute__((ext_vector_type(4)));

__device__ __forceinline__ unsigned short f2bf(float f) {
    unsigned u = __float_as_uint(f);
    unsigned r = (u + 0x7fffu + ((u >> 16) & 1u)) >> 16;   // RTN-even
    return (unsigned short)r;
}

// ---------------------------------------------------------------------------
// prep_all: ONE launch for all operand conversions (round-18, VERIFIED).
//   blocks [0,640):        memF   blocks [640,4480):  memS
//   blocks [4480,5632):    w12T   blocks [5632,6208): w2T
// ---------------------------------------------------------------------------
__global__ __launch_bounds__(256)
void prep_all(const float* __restrict__ mem, const float* __restrict__ w1,
              const float* __restrict__ w2,
              unsigned short* __restrict__ memF, unsigned short* __restrict__ memS,
              unsigned short* __restrict__ w12T, unsigned short* __restrict__ w2T)
{
    __shared__ float T[32][65];
    const int bid = blockIdx.x;

    if (bid < 640) {
        const int mb = bid;
        const bool zero = (mb >= MEMN / 16);
#pragma unroll
        for (int it = 0; it < 6; ++it) {
            const int s   = it * 256 + threadIdx.x;      // 0..1535
            const int kc  = s >> 6;
            const int r   = s & 63;
            const int l16 = r >> 2, q = r & 3;
            unsigned short o[8];
            if (!zero) {
                const float* src = &mem[(size_t)(mb * 16 + l16) * DIM + kc * 32 + q * 8];
                float4 v0 = *(const float4*)src;
                float4 v1 = *(const float4*)(src + 4);
                o[0] = f2bf(v0.x); o[1] = f2bf(v0.y); o[2] = f2bf(v0.z); o[3] = f2bf(v0.w);
                o[4] = f2bf(v1.x); o[5] = f2bf(v1.y); o[6] = f2bf(v1.z); o[7] = f2bf(v1.w);
            } else {
#pragma unroll
                for (int j = 0; j < 8; ++j) o[j] = 0;
            }
            *(uint4*)&memF[((size_t)mb * 24 + kc) * 512 + r * 8] = *(const uint4*)o;
        }
    } else if (bid < 4480) {
        const int rr = bid - 640;
        const int mc = rr % 320;
        const int d0 = (rr / 320) * 64;
        const int tx = threadIdx.x & 63;
        const int ty = threadIdx.x >> 6;
#pragma unroll
        for (int i = 0; i < 8; ++i) {
            const int row = ty + 4 * i;                  // 0..31
            const int m   = mc * 32 + row;
            T[row][tx] = (m < MEMN) ? mem[(size_t)m * DIM + d0 + tx] : 0.f;
        }
        __syncthreads();
        const int dbl = threadIdx.x >> 6;
        const int r   = threadIdx.x & 63;
        const int l16 = r >> 2, q = r & 3;
        unsigned short o[8];
#pragma unroll
        for (int j = 0; j < 8; ++j) o[j] = f2bf(T[q * 8 + j][dbl * 16 + l16]);
        *(uint4*)&memS[((size_t)(d0 / 16 + dbl) * 320 + mc) * 512 + r * 8] = *(const uint4*)o;
    } else if (bid < 5632) {
        const int rr = bid - 4480;
        const int kb = (rr % 48) * 32;
        const int nb = (rr / 48) * 32;
        const int tx = threadIdx.x & 31, ty = threadIdx.x >> 5;
#pragma unroll
        for (int i = 0; i < 4; ++i) {
            int k = kb + ty + 8 * i;
            float v = w1[(size_t)(768 + k) * DIM + nb + tx];
            if (kb < 768) v += w1[(size_t)k * DIM + nb + tx];
            T[ty + 8 * i][tx] = v;              // T[k_local][n_local]
        }
        __syncthreads();
        if (threadIdx.x < 128) {
            const int sub = threadIdx.x >> 6;
            const int r   = threadIdx.x & 63;
            const int l16 = r >> 2, q = r & 3;
            unsigned short o[8];
#pragma unroll
            for (int j = 0; j < 8; ++j) o[j] = f2bf(T[q * 8 + j][sub * 16 + l16]);
            const int n16 = (nb >> 4) + sub;
            const int kc  = kb >> 5;
            *(uint4*)&w12T[((size_t)n16 * 48 + kc) * 512 + r * 8] = *(const uint4*)o;
        }
    } else {
        const int rr = bid - 5632;
        const int kb = (rr % 24) * 32;
        const int nb = (rr / 24) * 32;
        const int tx = threadIdx.x & 31, ty = threadIdx.x >> 5;
#pragma unroll
        for (int i = 0; i < 4; ++i)
            T[ty + 8 * i][tx] = w2[(size_t)(kb + ty + 8 * i) * DIM + nb + tx];
        __syncthreads();
        if (threadIdx.x < 128) {
            const int sub = threadIdx.x >> 6;
            const int r   = threadIdx.x & 63;
            const int l16 = r >> 2, q = r & 3;
            unsigned short o[8];
#pragma unroll
            for (int j = 0; j < 8; ++j) o[j] = f2bf(T[q * 8 + j][sub * 16 + l16]);
            const int n16 = (nb >> 4) + sub;
            const int kc  = kb >> 5;
            *(uint4*)&w2T[((size_t)n16 * 24 + kc) * 512 + r * 8] = *(const uint4*)o;
        }
    }
}

// ---------------------------------------------------------------------------
// Fused MFMA attention. Round-15 main loop (VERIFIED 599-613 us) UNCHANGED.
// Q staged directly from fp32 cs.
// ---------------------------------------------------------------------------
template <int PLAIN>
__global__ __launch_bounds__(1024, 4)
void attn_mfma(const float* __restrict__ cs, const unsigned short* __restrict__ memF,
               const unsigned short* __restrict__ memS,
               float* __restrict__ retrRaw, float* __restrict__ Lvec)
{
    __shared__ __align__(16) unsigned short Qs[64 * 768];   // 96 KB, xor-swizzled
    __shared__ __align__(16) unsigned short Ps[64 * 256];   // 32 KB, xor-swizzled
    __shared__ float Lred[16][64];                          // 4 KB, L block-reduce

    const int tid    = threadIdx.x;
    const int w      = tid >> 6;         // wave 0..15
    const int lane   = tid & 63;
    const int quad   = lane >> 4;        // 0..3
    const int l16    = lane & 15;
    const int fr     = ((l16 << 2) | quad) << 3;   // fragment-linear lane offset (ushorts)

    const int split = blockIdx.y;
    const int q0    = blockIdx.x * TQ;   // 0..8128 step 64

    const int dbase  = w * 48;           // phase-2 d-strip per wave (3 x 16)
    const int mstrip = w * 16;           // phase-1 m-strip per wave (1 x 16)

    // ---- stage Q tile (64 rows) from fp32, convert to bf16, swizzled ----
    {
        const int qr  = tid >> 4;            // 0..63
        const int db0 = tid & 15;
        const float* src = cs + (size_t)(q0 + qr) * DIM;
        const int sw = qr & 7;
#pragma unroll
        for (int i = 0; i < 6; ++i) {
            int db = db0 + i * 16;           // 0..95 (blocks of 8 bf16)
            float4 v0 = *(const float4*)&src[db * 8];
            float4 v1 = *(const float4*)&src[db * 8 + 4];
            unsigned short o[8];
            o[0] = f2bf(v0.x); o[1] = f2bf(v0.y); o[2] = f2bf(v0.z); o[3] = f2bf(v0.w);
            o[4] = f2bf(v1.x); o[5] = f2bf(v1.y); o[6] = f2bf(v1.z); o[7] = f2bf(v1.w);
            *(uint4*)&Qs[qr * 768 + ((db ^ sw) << 3)] = *(const uint4*)o;
        }
    }
    __syncthreads();

    f32x4 oacc[4][3];
#pragma unroll
    for (int a = 0; a < 4; ++a)
#pragma unroll
        for (int b = 0; b < 3; ++b) oacc[a][b] = (f32x4){0.f, 0.f, 0.f, 0.f};
    float lsum[4][4];
#pragma unroll
    for (int a = 0; a < 4; ++a)
#pragma unroll
        for (int r = 0; r < 4; ++r) lsum[a][r] = 0.f;

    const int xsw = l16 & 7;

    for (int st = 0; st < TILES_PER_SPLIT; ++st) {
        const int m0  = (split * TILES_PER_SPLIT + st) * TM;
        const int mc0 = m0 >> 5;

        // ---- phase 1: S[64 x 256]; wave w covers m-strip mstrip..+16 ----
        f32x4 sacc[4];
#pragma unroll
        for (int a = 0; a < 4; ++a) sacc[a] = (f32x4){0.f, 0.f, 0.f, 0.f};

        const unsigned short* fb = memF + ((size_t)(m0 >> 4) + w) * 12288 + fr;

        bf16x8 pb[2];
        pb[0] = *(const bf16x8*)(fb);
        pb[1] = *(const bf16x8*)(fb + 512);

#pragma unroll
        for (int ks = 0; ks < 24; ++ks) {
            const int xq = (((ks << 2) + quad) ^ xsw) << 3;
            bf16x8 a0 = *(const bf16x8*)&Qs[l16 * 768 + xq];
            bf16x8 a1 = *(const bf16x8*)&Qs[(16 + l16) * 768 + xq];
            bf16x8 a2 = *(const bf16x8*)&Qs[(32 + l16) * 768 + xq];
            bf16x8 a3 = *(const bf16x8*)&Qs[(48 + l16) * 768 + xq];
            bf16x8 b = pb[ks & 1];
            sacc[0] = __builtin_amdgcn_mfma_f32_16x16x32_bf16(a0, b, sacc[0], 0, 0, 0);
            sacc[1] = __builtin_amdgcn_mfma_f32_16x16x32_bf16(a1, b, sacc[1], 0, 0, 0);
            sacc[2] = __builtin_amdgcn_mfma_f32_16x16x32_bf16(a2, b, sacc[2], 0, 0, 0);
            sacc[3] = __builtin_amdgcn_mfma_f32_16x16x32_bf16(a3, b, sacc[3], 0, 0, 0);
            if (ks < 22) pb[ks & 1] = *(const bf16x8*)(fb + (ks + 2) * 512);
        }

        __syncthreads();   // barrier A

        // ---- exp + P->LDS (bf16, swizzled) + row-sum accumulation ----
        {
            const int mloc = mstrip + l16;               // 0..255
            const bool ok  = (m0 + mloc) < MEMN;
#pragma unroll
            for (int qt = 0; qt < 4; ++qt)
#pragma unroll
                for (int r = 0; r < 4; ++r) {
                    float p = ok ? __expf(sacc[qt][r] * SCALE) : 0.f;
                    const int q = qt * 16 + quad * 4 + r;     // 0..63
                    lsum[qt][r] += p;
                    Ps[q * 256 + (((mloc >> 3) ^ (q & 7)) << 3) + (mloc & 7)] = f2bf(p);
                }
        }

        __syncthreads();   // barrier B

        // ---- phase 2: O += P * Mem; depth-2 register prefetch of B-frags ----
        const unsigned short* msp = memS + ((size_t)(3 * w) * 320 + mc0) * 512 + fr;
        bf16x8 cb[2][3];
#pragma unroll
        for (int nt = 0; nt < 3; ++nt) {
            cb[0][nt] = *(const bf16x8*)(msp + (size_t)nt * 163840);
            cb[1][nt] = *(const bf16x8*)(msp + (size_t)nt * 163840 + 512);
        }

#pragma unroll
        for (int ks = 0; ks < 8; ++ks) {
            const int xp = (((ks << 2) + quad) ^ xsw) << 3;
            bf16x8 pa0 = *(const bf16x8*)&Ps[l16 * 256 + xp];
            bf16x8 pa1 = *(const bf16x8*)&Ps[(16 + l16) * 256 + xp];
            bf16x8 pa2 = *(const bf16x8*)&Ps[(32 + l16) * 256 + xp];
            bf16x8 pa3 = *(const bf16x8*)&Ps[(48 + l16) * 256 + xp];
            const bool dopf = (ks < 6);
#pragma unroll
            for (int nt = 0; nt < 3; ++nt) {
                oacc[0][nt] = __builtin_amdgcn_mfma_f32_16x16x32_bf16(pa0, cb[ks & 1][nt], oacc[0][nt], 0, 0, 0);
                oacc[1][nt] = __builtin_amdgcn_mfma_f32_16x16x32_bf16(pa1, cb[ks & 1][nt], oacc[1][nt], 0, 0, 0);
                oacc[2][nt] = __builtin_amdgcn_mfma_f32_16x16x32_bf16(pa2, cb[ks & 1][nt], oacc[2][nt], 0, 0, 0);
                oacc[3][nt] = __builtin_amdgcn_mfma_f32_16x16x32_bf16(pa3, cb[ks & 1][nt], oacc[3][nt], 0, 0, 0);
                if (dopf) cb[ks & 1][nt] = *(const bf16x8*)(msp + (size_t)nt * 163840 + (ks + 2) * 512);
            }
        }
    }

    // ---- epilogue: combine O and L across splits ----
    float* ob = retrRaw + (PLAIN ? (size_t)split * ((size_t)N_TOK * DIM) : (size_t)0);
#pragma unroll
    for (int qt = 0; qt < 4; ++qt)
#pragma unroll
        for (int nt = 0; nt < 3; ++nt)
#pragma unroll
            for (int r = 0; r < 4; ++r) {
                const size_t idx = (size_t)(q0 + qt * 16 + quad * 4 + r) * DIM + dbase + nt * 16 + l16;
                if (PLAIN)
                    ob[idx] = oacc[qt][nt][r];
                else
                    __hip_atomic_fetch_add(&ob[idx], oacc[qt][nt][r],
                                           __ATOMIC_RELAXED, __HIP_MEMORY_SCOPE_AGENT);
            }

#pragma unroll
    for (int qt = 0; qt < 4; ++qt)
#pragma unroll
        for (int r = 0; r < 4; ++r) {
            float v = lsum[qt][r];
#pragma unroll
            for (int off = 1; off < 16; off <<= 1) v += __shfl_xor(v, off);
            if (l16 == 0) {
                if (PLAIN)
                    Lred[w][qt * 16 + quad * 4 + r] = v;
                else
                    __hip_atomic_fetch_add(&Lvec[q0 + qt * 16 + quad * 4 + r], v,
                                           __ATOMIC_RELAXED, __HIP_MEMORY_SCOPE_AGENT);
            }
        }
    if (PLAIN) {
        __syncthreads();
        if (tid < 64) {
            float s = 0.f;
#pragma unroll
            for (int ww = 0; ww < 16; ++ww) s += Lred[ww][tid];
            Lvec[(size_t)split * N_TOK + q0 + tid] = s;
        }
    }
}

// ---------------------------------------------------------------------------
// Fused tail, round-20: 32 rows/block (grid 256), 1024 thr (16 waves,
// 4 waves/SIMD), per-wave 3 n16-blocks x 2 row-tiles.  Halves the per-block
// weight stream (256 blocks x 3.5 MB instead of 512 -> L2 weight demand
// 1.8 GB -> 0.9 GB) and doubles B-frag reuse (2 MFMAs per load).
// LDS: XRl 96K + Hl 48K + red 4K = 148 KB, 1 block/CU.
// ---------------------------------------------------------------------------
template <int PLAIN>
__global__ __launch_bounds__(1024, 4)
void fused_tail(const float* __restrict__ retrRaw, const float* __restrict__ Lvec,
                const float* __restrict__ cs, const float* __restrict__ gw,
                const float* __restrict__ gb,
                const unsigned short* __restrict__ W12T, const float* __restrict__ fb1,
                const unsigned short* __restrict__ W2T,  const float* __restrict__ fb2,
                const float* __restrict__ gamma, const float* __restrict__ beta,
                float* __restrict__ out)
{
    __shared__ __align__(16) unsigned short XRl[6 * 8192];  // 96 KB: XR[32][1536] swizzled
    __shared__ __align__(16) unsigned short Hl[3 * 8192];   // 48 KB: h[32][768] swizzled
    __shared__ float red[2][16][32];                        // 4 KB

    const int tid  = threadIdx.x;
    const int w    = tid >> 6;           // wave 0..15
    const int lane = tid & 63;
    const int quad = lane >> 4;
    const int l16  = lane & 15;
    const int row0 = blockIdx.x * 32;
    const int nbase = w * 48;            // 3 x 16 output cols per wave
    const int xsw3 = l16 & 7;
    const int fr   = ((l16 << 2) | quad) << 3;     // fragment-linear lane offset
    const int nb16 = w * 3;                        // first n16-block of this wave

    // ================= stage 1: finalize 32 rows -> XRl =================
#pragma unroll
    for (int it = 0; it < 2; ++it) {
        const int rl = it * 16 + w;                // local row 0..31
        const int row = row0 + rl;
        const float lv = PLAIN ? (Lvec[row] + Lvec[N_TOK + row]) : Lvec[row];
        const float rli = 1.0f / lv;
        const float* rr  = retrRaw + (size_t)row * DIM;
        const float* rr1 = retrRaw + (size_t)N_TOK * DIM + (size_t)row * DIM;
        const float* cr  = cs + (size_t)row * DIM;

        float4 rv[3], cv[3];
        float d = 0.f;
#pragma unroll
        for (int i = 0; i < 3; ++i) {
            const int c4 = i * 256 + lane * 4;
            float4 r = *(const float4*)&rr[c4];
            if (PLAIN) {
                float4 r1 = *(const float4*)&rr1[c4];
                r.x += r1.x; r.y += r1.y; r.z += r1.z; r.w += r1.w;
            }
            r.x *= rli; r.y *= rli; r.z *= rli; r.w *= rli;
            float4 c = *(const float4*)&cr[c4];
            float4 g1 = *(const float4*)&gw[c4];
            float4 g2 = *(const float4*)&gw[DIM + c4];
            d += c.x * g1.x + c.y * g1.y + c.z * g1.z + c.w * g1.w;
            d += r.x * g2.x + r.y * g2.y + r.z * g2.z + r.w * g2.w;
            rv[i] = r; cv[i] = c;
        }
#pragma unroll
        for (int off = 32; off > 0; off >>= 1) d += __shfl_xor(d, off);
        d += gb[0];
        const float g = 1.0f / (1.0f + __expf(-d));

        const int g8 = lane >> 1;                  // granule within 256-chunk
        const int lo = (lane & 1) * 4;
#pragma unroll
        for (int i = 0; i < 3; ++i) {
            ushort4 xo, ro;
            xo.x = f2bf(cv[i].x + g * rv[i].x); xo.y = f2bf(cv[i].y + g * rv[i].y);
            xo.z = f2bf(cv[i].z + g * rv[i].z); xo.w = f2bf(cv[i].w + g * rv[i].w);
            ro.x = f2bf(rv[i].x); ro.y = f2bf(rv[i].y);
            ro.z = f2bf(rv[i].z); ro.w = f2bf(rv[i].w);
            const int sw = ((g8 ^ (rl & 7)) << 3) + lo;
            *(ushort4*)&XRl[i * 8192 + rl * 256 + sw] = xo;
            *(ushort4*)&XRl[(3 + i) * 8192 + rl * 256 + sw] = ro;
        }
    }
    __syncthreads();

    // ================= stage 2: gemm1 (XRl @ W12T + b1 -> gelu -> Hl) =====
    f32x4 acc[2][3];
#pragma unroll
    for (int rt = 0; rt < 2; ++rt)
#pragma unroll
        for (int nt = 0; nt < 3; ++nt) acc[rt][nt] = (f32x4){0.f, 0.f, 0.f, 0.f};

    bf16x8 b[3];
#pragma unroll
    for (int nt = 0; nt < 3; ++nt)
        b[nt] = *(const bf16x8*)&W12T[(size_t)(nb16 + nt) * 48 * 512 + fr];

#pragma unroll
    for (int ch = 0; ch < 6; ++ch) {
#pragma unroll
        for (int ks = 0; ks < 8; ++ks) {
            const int xg = ((((ks << 2) + quad) ^ xsw3) << 3);
            bf16x8 af0 = *(const bf16x8*)&XRl[ch * 8192 + l16 * 256 + xg];
            bf16x8 af1 = *(const bf16x8*)&XRl[ch * 8192 + (16 + l16) * 256 + xg];
            int kn = ch * 8 + ks + 1;
            if (kn >= 48) kn = 0;                  // dummy wrap
#pragma unroll
            for (int nt = 0; nt < 3; ++nt) {
                acc[0][nt] = __builtin_amdgcn_mfma_f32_16x16x32_bf16(af0, b[nt], acc[0][nt], 0, 0, 0);
                acc[1][nt] = __builtin_amdgcn_mfma_f32_16x16x32_bf16(af1, b[nt], acc[1][nt], 0, 0, 0);
                b[nt] = *(const bf16x8*)&W12T[((size_t)(nb16 + nt) * 48 + kn) * 512 + fr];
            }
        }
    }

    {
        float bv[3];
#pragma unroll
        for (int nt = 0; nt < 3; ++nt) bv[nt] = fb1[nbase + nt * 16 + l16];
#pragma unroll
        for (int nt = 0; nt < 3; ++nt) {
            const int col = nbase + nt * 16 + l16;
            const int cch = col >> 8;
            const int g8  = (col >> 3) & 31;
#pragma unroll
            for (int rt = 0; rt < 2; ++rt)
#pragma unroll
                for (int r = 0; r < 4; ++r) {
                    const int rowl = rt * 16 + quad * 4 + r;
                    float v = acc[rt][nt][r] + bv[nt];
                    v = 0.5f * v * (1.0f + erff(v * 0.7071067811865476f));
                    Hl[cch * 8192 + rowl * 256 + ((g8 ^ (rowl & 7)) << 3) + (l16 & 7)] = f2bf(v);
                }
        }
    }

    // prefetch gemm2 B while Hl writes drain
    bf16x8 b2[3];
#pragma unroll
    for (int nt = 0; nt < 3; ++nt)
        b2[nt] = *(const bf16x8*)&W2T[(size_t)(nb16 + nt) * 24 * 512 + fr];

    __syncthreads();

    // ================= stage 3: gemm2 (Hl @ W2T + b2 -> LayerNorm -> out) ==
    f32x4 acc2[2][3];
#pragma unroll
    for (int rt = 0; rt < 2; ++rt)
#pragma unroll
        for (int nt = 0; nt < 3; ++nt) acc2[rt][nt] = (f32x4){0.f, 0.f, 0.f, 0.f};

#pragma unroll
    for (int ch = 0; ch < 3; ++ch) {
#pragma unroll
        for (int ks = 0; ks < 8; ++ks) {
            const int xg = ((((ks << 2) + quad) ^ xsw3) << 3);
            bf16x8 af0 = *(const bf16x8*)&Hl[ch * 8192 + l16 * 256 + xg];
            bf16x8 af1 = *(const bf16x8*)&Hl[ch * 8192 + (16 + l16) * 256 + xg];
            int kn = ch * 8 + ks + 1;
            if (kn >= 24) kn = 0;                  // dummy wrap
#pragma unroll
            for (int nt = 0; nt < 3; ++nt) {
                acc2[0][nt] = __builtin_amdgcn_mfma_f32_16x16x32_bf16(af0, b2[nt], acc2[0][nt], 0, 0, 0);
                acc2[1][nt] = __builtin_amdgcn_mfma_f32_16x16x32_bf16(af1, b2[nt], acc2[1][nt], 0, 0, 0);
                b2[nt] = *(const bf16x8*)&W2T[((size_t)(nb16 + nt) * 24 + kn) * 512 + fr];
            }
        }
    }

    {
        float bv[3];
#pragma unroll
        for (int nt = 0; nt < 3; ++nt) bv[nt] = fb2[nbase + nt * 16 + l16];

        float v[2][3][4];
        float s1[2][4], s2[2][4];
#pragma unroll
        for (int rt = 0; rt < 2; ++rt)
#pragma unroll
            for (int r = 0; r < 4; ++r) { s1[rt][r] = 0.f; s2[rt][r] = 0.f; }
#pragma unroll
        for (int rt = 0; rt < 2; ++rt)
#pragma unroll
            for (int nt = 0; nt < 3; ++nt)
#pragma unroll
                for (int r = 0; r < 4; ++r) {
                    float t = acc2[rt][nt][r] + bv[nt];
                    v[rt][nt][r] = t;
                    s1[rt][r] += t;
                    s2[rt][r] += t * t;
                }
#pragma unroll
        for (int rt = 0; rt < 2; ++rt)
#pragma unroll
            for (int r = 0; r < 4; ++r) {
#pragma unroll
                for (int off = 1; off < 16; off <<= 1) {
                    s1[rt][r] += __shfl_xor(s1[rt][r], off);
                    s2[rt][r] += __shfl_xor(s2[rt][r], off);
                }
                if (l16 == 0) {
                    red[0][w][rt * 16 + quad * 4 + r] = s1[rt][r];
                    red[1][w][rt * 16 + quad * 4 + r] = s2[rt][r];
                }
            }
        __syncthreads();
#pragma unroll
        for (int rt = 0; rt < 2; ++rt)
#pragma unroll
            for (int r = 0; r < 4; ++r) {
                const int rl = rt * 16 + quad * 4 + r;
                float t1 = 0.f, t2 = 0.f;
#pragma unroll
                for (int ww = 0; ww < 16; ++ww) {
                    t1 += red[0][ww][rl];
                    t2 += red[1][ww][rl];
                }
                const float mu  = t1 * (1.0f / 768.0f);
                const float var = fmaxf(t2 * (1.0f / 768.0f) - mu * mu, 0.f);
                const float rs  = rsqrtf(var + 1e-5f);
                const int row = row0 + rl;
#pragma unroll
                for (int nt = 0; nt < 3; ++nt) {
                    const int col = nbase + nt * 16 + l16;
                    out[(size_t)row * DIM + col] = (v[rt][nt][r] - mu) * rs * gamma[col] + beta[col];
                }
            }
    }
}

// ---------------------------------------------------------------------------
extern "C" void kernel_launch(void* const* d_in, const int* in_sizes, int n_in,
                              void* d_out, int out_size, void* d_ws, size_t ws_size,
                              hipStream_t stream)
{
    const float* cs  = (const float*)d_in[0];
    const float* mem = (const float*)d_in[1];
    const float* gw  = (const float*)d_in[2];
    const float* gb  = (const float*)d_in[3];
    const float* fw1 = (const float*)d_in[4];
    const float* fb1 = (const float*)d_in[5];
    const float* fw2 = (const float*)d_in[6];
    const float* fb2 = (const float*)d_in[7];
    const float* gam = (const float*)d_in[8];
    const float* bet = (const float*)d_in[9];
    float* out = (float*)d_out;

    char* ws = (char*)d_ws;
    // Layout A (atomic fallback, ~72.8 MB) / Layout B (plain, ~98 MB):
    const size_t PLAIN_WS = 97976320;
    const bool plain = (ws_size >= PLAIN_WS);

    unsigned short* memF = (unsigned short*)ws;                 // 15,728,640
    unsigned short* memS = (unsigned short*)(ws + 15728640);    // 15,728,640
    // (qH region ws+31457280..44040192 unused; kept for layout stability)
    float*          retr = (float*)(ws + 44040192);             // A: 25,165,824 / B: 50,331,648
    float*          Lvec;
    unsigned short* w12T;
    unsigned short* w2T;
    if (plain) {
        Lvec = (float*)(ws + 94371840);            // 65,536 (2 splits)
        w12T = (unsigned short*)(ws + 94437376);   // 2,359,296
        w2T  = (unsigned short*)(ws + 96796672);   // 1,179,648 -> end 97,976,320
    } else {
        Lvec = (float*)(ws + 69206016);            // 32,768
        w12T = (unsigned short*)(ws + 69238784);   // 2,359,296
        w2T  = (unsigned short*)(ws + 71598080);   // 1,179,648 -> end 72,777,728
    }

    if (!plain)
        hipMemsetAsync(retr, 0, 25165824 + 32768, stream);      // atomic path needs zeroed accum

    prep_all<<<6208, 256, 0, stream>>>(mem, fw1, fw2, memF, memS, w12T, w2T);

    if (plain) {
        attn_mfma<1><<<dim3(N_TOK / TQ, NSPLIT), 1024, 0, stream>>>(cs, memF, memS, retr, Lvec);
        fused_tail<1><<<N_TOK / 32, 1024, 0, stream>>>(retr, Lvec, cs, gw, gb,
                                                       w12T, fb1, w2T, fb2, gam, bet, out);
    } else {
        attn_mfma<0><<<dim3(N_TOK / TQ, NSPLIT), 1024, 0, stream>>>(cs, memF, memS, retr, Lvec);
        fused_tail<0><<<N_TOK / 32, 1024, 0, stream>>>(retr, Lvec, cs, gw, gb,
                                                       w12T, fb1, w2T, fb2, gam, bet, out);
    }
}